// Round 2
// baseline (180.482 us; speedup 1.0000x reference)
//
#include <hip/hip_runtime.h>
#include <hip/hip_bf16.h>

// Problem: B=32, L=256, K=8, E=768, V=50000 ; M = B*L = 8192
// inputs: hidden [M,E] f32, similar_words [M,K] int32, word2vec [V,E] f32, weight [E,E] f32
// out:    [M,E] f32
//
// Plan: qproj = hidden @ weight via split-bf16 MFMA (hi/lo compensated, 3 MFMAs),
// then fused gather/softmax/weighted-sum. qproj staged through d_out (attn reads
// its row into regs before overwriting). bf16 operand copies live in d_ws.

typedef __attribute__((ext_vector_type(8))) short bf16x8;   // 8 bf16 = 4 VGPRs (guide §3)
typedef __attribute__((ext_vector_type(4))) float f32x4;

__device__ __forceinline__ unsigned short f2bf(float f) {   // RNE f32 -> bf16
    unsigned int u = __float_as_uint(f);
    u += 0x7FFFu + ((u >> 16) & 1u);
    return (unsigned short)(u >> 16);
}
__device__ __forceinline__ float bf2f(unsigned short h) {
    return __uint_as_float(((unsigned int)h) << 16);
}

// ---------------- conversion pre-passes ----------------

// x[n4*4] f32 -> hi/lo bf16, same layout. Vectorized float4 in, ushort4 out.
__global__ __launch_bounds__(256) void split_bf16(const float4* __restrict__ x,
                                                  ushort4* __restrict__ hi,
                                                  ushort4* __restrict__ lo, int n4) {
    int i = blockIdx.x * 256 + threadIdx.x;
    const int stride = gridDim.x * 256;
    for (; i < n4; i += stride) {
        float4 v = x[i];
        ushort4 h, l;
        h.x = f2bf(v.x); l.x = f2bf(v.x - bf2f(h.x));
        h.y = f2bf(v.y); l.y = f2bf(v.y - bf2f(h.y));
        h.z = f2bf(v.z); l.z = f2bf(v.z - bf2f(h.z));
        h.w = f2bf(v.w); l.w = f2bf(v.w - bf2f(h.w));
        hi[i] = h; lo[i] = l;
    }
}

// W[K][N] f32 -> hiT/loT bf16 [N][K] (transposed so GEMM B-frags are K-contiguous).
__global__ __launch_bounds__(256) void split_bf16_T(const float* __restrict__ W,
                                                    unsigned short* __restrict__ hiT,
                                                    unsigned short* __restrict__ loT,
                                                    int K, int N) {
    __shared__ float tile[32][33];
    const int bk = blockIdx.x * 32, bn = blockIdx.y * 32;
    const int tx = threadIdx.x & 31, ty = threadIdx.x >> 5;   // 32 x 8
#pragma unroll
    for (int r = ty; r < 32; r += 8)
        tile[r][tx] = W[(size_t)(bk + r) * N + bn + tx];
    __syncthreads();
#pragma unroll
    for (int r = ty; r < 32; r += 8) {
        float v = tile[tx][r];                 // = W[bk+tx][bn+r]
        unsigned short h = f2bf(v);
        size_t o = (size_t)(bn + r) * K + bk + tx;
        hiT[o] = h;
        loT[o] = f2bf(v - bf2f(h));
    }
}

// ---------------- split-bf16 MFMA GEMM ----------------
// C[M][N] = A[M][K] * B[K][N], A given as Ahi/Alo [M][K], B as BhiT/BloT [N][K].
// Tile 128x64, BK=64, 256 threads = 4 waves in 2x2; wave does 4x2 16x16 frags.

#define BM 128
#define BN 64
#define BK 64

__global__ __launch_bounds__(256) void gemm_mfma_split(
        const unsigned short* __restrict__ Ahi, const unsigned short* __restrict__ Alo,
        const unsigned short* __restrict__ BhiT, const unsigned short* __restrict__ BloT,
        float* __restrict__ C, int M, int N, int K) {

    // XCD-aware swizzle (nwg = 768, %8==0): logical-consecutive tiles share an XCD,
    // so the 12 tiles sharing one A-panel co-locate in one L2.
    const int nwg = gridDim.x;
    const int per = nwg >> 3;
    const int l   = (blockIdx.x & 7) * per + (blockIdx.x >> 3);
    const int nbn = N / BN;
    const int bm  = (l / nbn) * BM;
    const int bn  = (l % nbn) * BN;

    // LDS in 16B slots: Ahi[8][128], Alo[8][128], Bhi[8][64], Blo[8][64]  (48 KiB)
    __shared__ unsigned short lds[3072 * 8];
    const int AHI = 0, ALO = 1024, BHI = 2048, BLO = 2560;

    const int tid  = threadIdx.x;
    const int lane = tid & 63;
    const int wave = tid >> 6;
    const int wm = wave >> 1, wn = wave & 1;
    const int lr = lane & 15, lg = lane >> 4;

    f32x4 acc[4][2];
#pragma unroll
    for (int m = 0; m < 4; ++m)
#pragma unroll
        for (int n = 0; n < 2; ++n) acc[m][n] = (f32x4){0.f, 0.f, 0.f, 0.f};

    // Staging decode. A: 1024 16B-chunks (row=c>>3, kc=c&7), 4/thread.
    // LDS slot = kc*WIDTH + (row ^ kc)  -> write: kc varies at fixed row hits
    // distinct banks; read: XOR permutes within a 16-row group (kc<8<=16).
    int arow[4], aslot[4];
    long aoff[4];
#pragma unroll
    for (int t = 0; t < 4; ++t) {
        int c = tid + t * 256;
        int row = c >> 3, kc = c & 7;
        arow[t] = row; aslot[t] = kc * 128 + (row ^ kc);
        aoff[t] = (long)kc * 8;
    }
    int bslot[2]; int brow[2]; long boff[2];
#pragma unroll
    for (int t = 0; t < 2; ++t) {
        int c = tid + t * 256;
        int row = c >> 3, kc = c & 7;
        brow[t] = row; bslot[t] = kc * 64 + (row ^ kc);
        boff[t] = (long)kc * 8;
    }

    uint4 rah[4], ral[4], rbh[2], rbl[2];
    auto LD = [&](int k0) {
#pragma unroll
        for (int t = 0; t < 4; ++t) {
            size_t g = (size_t)(bm + arow[t]) * K + k0 + aoff[t];
            rah[t] = *(const uint4*)(Ahi + g);
            ral[t] = *(const uint4*)(Alo + g);
        }
#pragma unroll
        for (int t = 0; t < 2; ++t) {
            size_t g = (size_t)(bn + brow[t]) * K + k0 + boff[t];
            rbh[t] = *(const uint4*)(BhiT + g);
            rbl[t] = *(const uint4*)(BloT + g);
        }
    };

    LD(0);
    const int niter = K / BK;
    for (int it = 0; it < niter; ++it) {
        __syncthreads();   // previous compute finished reading LDS
#pragma unroll
        for (int t = 0; t < 4; ++t) {
            *(uint4*)&lds[(AHI + aslot[t]) * 8] = rah[t];
            *(uint4*)&lds[(ALO + aslot[t]) * 8] = ral[t];
        }
#pragma unroll
        for (int t = 0; t < 2; ++t) {
            *(uint4*)&lds[(BHI + bslot[t]) * 8] = rbh[t];
            *(uint4*)&lds[(BLO + bslot[t]) * 8] = rbl[t];
        }
        __syncthreads();
        if (it + 1 < niter) LD((it + 1) * BK);   // prefetch overlaps compute

#pragma unroll
        for (int ks = 0; ks < 2; ++ks) {
            const int kc = ks * 4 + lg;          // this lane-group's K chunk
            bf16x8 ah[4], al[4], bh[2], bl[2];
#pragma unroll
            for (int m = 0; m < 4; ++m) {
                int slot = kc * 128 + ((wm * 64 + m * 16 + lr) ^ kc);
                ah[m] = *(const bf16x8*)&lds[(AHI + slot) * 8];
                al[m] = *(const bf16x8*)&lds[(ALO + slot) * 8];
            }
#pragma unroll
            for (int n = 0; n < 2; ++n) {
                int slot = kc * 64 + ((wn * 32 + n * 16 + lr) ^ kc);
                bh[n] = *(const bf16x8*)&lds[(BHI + slot) * 8];
                bl[n] = *(const bf16x8*)&lds[(BLO + slot) * 8];
            }
#pragma unroll
            for (int m = 0; m < 4; ++m)
#pragma unroll
                for (int n = 0; n < 2; ++n) {
                    acc[m][n] = __builtin_amdgcn_mfma_f32_16x16x32_bf16(ah[m], bh[n], acc[m][n], 0, 0, 0);
                    acc[m][n] = __builtin_amdgcn_mfma_f32_16x16x32_bf16(al[m], bh[n], acc[m][n], 0, 0, 0);
                    acc[m][n] = __builtin_amdgcn_mfma_f32_16x16x32_bf16(ah[m], bl[n], acc[m][n], 0, 0, 0);
                }
        }
    }

    // Epilogue: C/D layout col=lane&15, row=(lane>>4)*4+reg  [m89/m91]
#pragma unroll
    for (int m = 0; m < 4; ++m)
#pragma unroll
        for (int n = 0; n < 2; ++n) {
            const int col = bn + wn * 32 + n * 16 + lr;
            const int r0  = bm + wm * 64 + m * 16 + lg * 4;
#pragma unroll
            for (int j = 0; j < 4; ++j)
                C[(size_t)(r0 + j) * N + col] = acc[m][n][j];
        }
}

// ---------------- fallback f32 GEMM (if ws too small) ----------------
#define GM_BM 128
#define GM_BN 64
#define GM_BK 16
#define GM_TM 8
#define GM_TN 4

__global__ __launch_bounds__(256) void gemm_qproj(const float* __restrict__ A,
                                                  const float* __restrict__ B,
                                                  float* __restrict__ C,
                                                  int M, int N, int K) {
    __shared__ float As[GM_BK][GM_BM];
    __shared__ float Bs[GM_BK][GM_BN];
    const int tid = threadIdx.x;
    const int tx = tid & 15;
    const int ty = tid >> 4;
    const int bm = blockIdx.x * GM_BM;
    const int bn = blockIdx.y * GM_BN;
    float acc[GM_TM][GM_TN];
#pragma unroll
    for (int i = 0; i < GM_TM; ++i)
#pragma unroll
        for (int j = 0; j < GM_TN; ++j) acc[i][j] = 0.f;
    for (int k0 = 0; k0 < K; k0 += GM_BK) {
#pragma unroll
        for (int i = 0; i < 2; ++i) {
            int idx = tid * 2 + i;
            int row = idx >> 2;
            int c4  = idx & 3;
            float4 v = *(const float4*)(A + (size_t)(bm + row) * K + k0 + c4 * 4);
            As[c4 * 4 + 0][row] = v.x;
            As[c4 * 4 + 1][row] = v.y;
            As[c4 * 4 + 2][row] = v.z;
            As[c4 * 4 + 3][row] = v.w;
        }
        {
            int row = tid >> 4;
            int c4  = tid & 15;
            float4 v = *(const float4*)(B + (size_t)(k0 + row) * N + bn + c4 * 4);
            *(float4*)&Bs[row][c4 * 4] = v;
        }
        __syncthreads();
#pragma unroll
        for (int k = 0; k < GM_BK; ++k) {
            float a[GM_TM], b[GM_TN];
#pragma unroll
            for (int i = 0; i < GM_TM; ++i) a[i] = As[k][ty * GM_TM + i];
#pragma unroll
            for (int j = 0; j < GM_TN; ++j) b[j] = Bs[k][tx * GM_TN + j];
#pragma unroll
            for (int i = 0; i < GM_TM; ++i)
#pragma unroll
                for (int j = 0; j < GM_TN; ++j) acc[i][j] += a[i] * b[j];
        }
        __syncthreads();
    }
#pragma unroll
    for (int i = 0; i < GM_TM; ++i) {
        float4 v;
        v.x = acc[i][0]; v.y = acc[i][1]; v.z = acc[i][2]; v.w = acc[i][3];
        *(float4*)(C + (size_t)(bm + ty * GM_TM + i) * N + bn + tx * GM_TN) = v;
    }
}

// ---------------- fused gather / score / softmax / output ----------------
__global__ __launch_bounds__(256) void attn_fused(const float* __restrict__ qproj,
                                                  const int* __restrict__ sws,
                                                  const float* __restrict__ w2v,
                                                  float* __restrict__ out) {
    const int wave = threadIdx.x >> 6;
    const int lane = threadIdx.x & 63;
    const size_t row = (size_t)blockIdx.x * 4 + wave;

    const float4* q4 = (const float4*)(qproj + row * 768);
    float4 q[3];
#pragma unroll
    for (int j = 0; j < 3; ++j) q[j] = q4[j * 64 + lane];

    float4 ks[8][3];
    float dot[8];
#pragma unroll
    for (int k = 0; k < 8; ++k) {
        int id = sws[row * 8 + k];
        const float4* kp = (const float4*)(w2v + (size_t)id * 768);
        float d = 0.f;
#pragma unroll
        for (int j = 0; j < 3; ++j) {
            float4 v = kp[j * 64 + lane];
            ks[k][j] = v;
            d += q[j].x * v.x;
            d += q[j].y * v.y;
            d += q[j].z * v.z;
            d += q[j].w * v.w;
        }
        dot[k] = d;
    }
#pragma unroll
    for (int k = 0; k < 8; ++k) {
        float d = dot[k];
#pragma unroll
        for (int m = 1; m < 64; m <<= 1) d += __shfl_xor(d, m);
        dot[k] = d;
    }
    float mx = dot[0];
#pragma unroll
    for (int k = 1; k < 8; ++k) mx = fmaxf(mx, dot[k]);
    float w[8];
    float s = 0.f;
#pragma unroll
    for (int k = 0; k < 8; ++k) { w[k] = __expf(dot[k] - mx); s += w[k]; }
    const float inv = 1.f / s;

    float4 o[3];
#pragma unroll
    for (int j = 0; j < 3; ++j) { o[j].x = 0.f; o[j].y = 0.f; o[j].z = 0.f; o[j].w = 0.f; }
#pragma unroll
    for (int k = 0; k < 8; ++k) {
        const float a = w[k] * inv;
#pragma unroll
        for (int j = 0; j < 3; ++j) {
            o[j].x += a * ks[k][j].x;
            o[j].y += a * ks[k][j].y;
            o[j].z += a * ks[k][j].z;
            o[j].w += a * ks[k][j].w;
        }
    }
    float4* o4 = (float4*)(out + row * 768);
#pragma unroll
    for (int j = 0; j < 3; ++j) o4[j * 64 + lane] = o[j];
}

extern "C" void kernel_launch(void* const* d_in, const int* in_sizes, int n_in,
                              void* d_out, int out_size, void* d_ws, size_t ws_size,
                              hipStream_t stream) {
    const float* hidden = (const float*)d_in[0];
    const int*   sws    = (const int*)d_in[1];
    const float* w2v    = (const float*)d_in[2];
    const float* weight = (const float*)d_in[3];
    float*       out    = (float*)d_out;

    const int E = 768;
    const int M = in_sizes[0] / E;            // 8192
    float* qproj = out;                        // staged through d_out

    const size_t szA = (size_t)M * E * sizeof(unsigned short);   // 12.58 MB
    const size_t szB = (size_t)E * E * sizeof(unsigned short);   // 1.18 MB
    const size_t need = 2 * szA + 2 * szB;

    if (ws_size >= need) {
        unsigned short* Ahi  = (unsigned short*)d_ws;
        unsigned short* Alo  = Ahi + (size_t)M * E;
        unsigned short* BhiT = Alo + (size_t)M * E;
        unsigned short* BloT = BhiT + (size_t)E * E;

        split_bf16<<<2048, 256, 0, stream>>>((const float4*)hidden,
                                             (ushort4*)Ahi, (ushort4*)Alo,
                                             M * E / 4);
        split_bf16_T<<<dim3(E / 32, E / 32), 256, 0, stream>>>(weight, BhiT, BloT, E, E);

        dim3 ggrid((M / BM) * (E / BN));      // 64*12 = 768, %8==0
        gemm_mfma_split<<<ggrid, 256, 0, stream>>>(Ahi, Alo, BhiT, BloT, qproj, M, E, E);
    } else {
        dim3 ggrid(M / GM_BM, E / GM_BN);
        gemm_qproj<<<ggrid, 256, 0, stream>>>(hidden, weight, qproj, M, E, E);
    }

    attn_fused<<<dim3(M / 4), 256, 0, stream>>>(qproj, sws, w2v, out);
}

// Round 3
// 83.220 us; speedup vs baseline: 2.1687x; 2.1687x over previous
//
#include <hip/hip_runtime.h>
#include <hip/hip_bf16.h>

// Problem: B=32, L=256, K=8, E=768, V=50000 ; M = B*L = 8192
// inputs: hidden [M,E] f32, similar_words [M,K] int32, word2vec [V,E] f32, weight [E,E] f32
// out:    [M,E] f32
//
// qproj = hidden @ weight via split-bf16 (hi/lo) MFMA, staged with
// global_load_lds (m97 structure) + source-side swizzle (rule 21);
// then fused gather/softmax/weighted-sum. qproj staged through d_out.

typedef __attribute__((ext_vector_type(8))) short bf16x8;   // 8 bf16 = 4 VGPRs
typedef __attribute__((ext_vector_type(4))) float f32x4;

__device__ __forceinline__ unsigned short f2bf(float f) {   // RNE f32 -> bf16
    unsigned int u = __float_as_uint(f);
    u += 0x7FFFu + ((u >> 16) & 1u);
    return (unsigned short)(u >> 16);
}
__device__ __forceinline__ float bf2f(unsigned short h) {
    return __uint_as_float(((unsigned int)h) << 16);
}

// async global->LDS, 16B per lane; LDS dest = wave-uniform base + lane*16.
__device__ __forceinline__ void gload16(const void* g, void* l) {
    __builtin_amdgcn_global_load_lds(
        (const __attribute__((address_space(1))) unsigned int*)g,
        (__attribute__((address_space(3))) unsigned int*)l, 16, 0, 0);
}

// ---------------- conversion pre-passes ----------------

__global__ __launch_bounds__(256) void split_bf16(const float4* __restrict__ x,
                                                  ushort4* __restrict__ hi,
                                                  ushort4* __restrict__ lo, int n4) {
    int i = blockIdx.x * 256 + threadIdx.x;
    const int stride = gridDim.x * 256;
    for (; i < n4; i += stride) {
        float4 v = x[i];
        ushort4 h, l;
        h.x = f2bf(v.x); l.x = f2bf(v.x - bf2f(h.x));
        h.y = f2bf(v.y); l.y = f2bf(v.y - bf2f(h.y));
        h.z = f2bf(v.z); l.z = f2bf(v.z - bf2f(h.z));
        h.w = f2bf(v.w); l.w = f2bf(v.w - bf2f(h.w));
        hi[i] = h; lo[i] = l;
    }
}

// W[K][N] f32 -> hiT/loT bf16 [N][K]
__global__ __launch_bounds__(256) void split_bf16_T(const float* __restrict__ W,
                                                    unsigned short* __restrict__ hiT,
                                                    unsigned short* __restrict__ loT,
                                                    int K, int N) {
    __shared__ float tile[32][33];
    const int bk = blockIdx.x * 32, bn = blockIdx.y * 32;
    const int tx = threadIdx.x & 31, ty = threadIdx.x >> 5;
#pragma unroll
    for (int r = ty; r < 32; r += 8)
        tile[r][tx] = W[(size_t)(bk + r) * N + bn + tx];
    __syncthreads();
#pragma unroll
    for (int r = ty; r < 32; r += 8) {
        float v = tile[tx][r];
        unsigned short h = f2bf(v);
        size_t o = (size_t)(bn + r) * K + bk + tx;
        hiT[o] = h;
        loT[o] = f2bf(v - bf2f(h));
    }
}

// ---------------- split-bf16 MFMA GEMM, global_load_lds staging ----------------
// C[M][N] = A[M][K]*B[K][N]; A as Ahi/Alo [M][K], B as BhiT/BloT [N][K].
// Tile 128x64, BK=64 (8 chunks of 8 bf16), 4 waves (2x2), wave = 4x2 16x16 frags.
// LDS 16B-slot regions: AHI[128*8] @0, ALO @1024, BHI[64*8] @2048, BLO @2560.
// Slot map: slot = row*8 + (kc ^ (row&7)); written linearly by gload_lds with
// the inverse swizzle applied to the per-lane GLOBAL address (rule 21).

#define BM 128
#define BN 64
#define BK 64

__global__ __launch_bounds__(256) void gemm_mfma_glds(
        const unsigned short* __restrict__ Ahi, const unsigned short* __restrict__ Alo,
        const unsigned short* __restrict__ BhiT, const unsigned short* __restrict__ BloT,
        float* __restrict__ C, int M, int N, int K) {

    // XCD-aware swizzle (nwg=768, %8==0): 12 tiles sharing an A-panel -> one XCD L2.
    const int nwg = gridDim.x;
    const int per = nwg >> 3;
    const int l   = (blockIdx.x & 7) * per + (blockIdx.x >> 3);
    const int nbn = N / BN;
    const int bm  = (l / nbn) * BM;
    const int bn  = (l % nbn) * BN;

    __shared__ unsigned short lds[3072 * 8];   // 48 KiB

    const int tid  = threadIdx.x;
    const int lane = tid & 63;
    const int w    = tid >> 6;                  // wave 0..3
    const int lr   = lane & 15, lg = lane >> 4;
    const int wm   = w >> 1, wn = w & 1;

    const int lane8 = lane >> 3;                // 0..7
    const int kcl   = (lane & 7) ^ lane8;       // staging: this lane's kc (pre-swizzle)

    f32x4 acc[4][2];
#pragma unroll
    for (int m = 0; m < 4; ++m)
#pragma unroll
        for (int n = 0; n < 2; ++n) acc[m][n] = (f32x4){0.f, 0.f, 0.f, 0.f};

    const int niter = K / BK;
    for (int it = 0; it < niter; ++it) {
        const int k0 = it * BK;

        // ---- stage tile via global_load_lds (12 issues/wave) ----
#pragma unroll
        for (int i = 0; i < 4; ++i) {
            size_t g = (size_t)(bm + 32 * w + 8 * i + lane8) * K + k0 + kcl * 8;
            gload16(Ahi + g, &lds[(size_t)(       256 * w + 64 * i) * 8]);
            gload16(Alo + g, &lds[(size_t)(1024 + 256 * w + 64 * i) * 8]);
        }
#pragma unroll
        for (int i = 0; i < 2; ++i) {
            size_t g = (size_t)(bn + 16 * w + 8 * i + lane8) * K + k0 + kcl * 8;
            gload16(BhiT + g, &lds[(size_t)(2048 + 128 * w + 64 * i) * 8]);
            gload16(BloT + g, &lds[(size_t)(2560 + 128 * w + 64 * i) * 8]);
        }
        __syncthreads();    // implicit vmcnt(0) drain -> LDS ready

        // ---- compute: 2 K-slices x (12 ds_read_b128 + 24 MFMA) ----
#pragma unroll
        for (int ks = 0; ks < 2; ++ks) {
            const int kc = ks * 4 + lg;
            const int kx = kc ^ (lr & 7);       // row&7 == lr&7 for all frag rows
            bf16x8 ah[4], al[4], bh[2], bl[2];
#pragma unroll
            for (int m = 0; m < 4; ++m) {
                int slot = (wm * 64 + m * 16 + lr) * 8 + kx;
                ah[m] = *(const bf16x8*)&lds[(size_t)slot * 8];
                al[m] = *(const bf16x8*)&lds[(size_t)(1024 + slot) * 8];
            }
#pragma unroll
            for (int n = 0; n < 2; ++n) {
                int slot = (wn * 32 + n * 16 + lr) * 8 + kx;
                bh[n] = *(const bf16x8*)&lds[(size_t)(2048 + slot) * 8];
                bl[n] = *(const bf16x8*)&lds[(size_t)(2560 + slot) * 8];
            }
#pragma unroll
            for (int m = 0; m < 4; ++m)
#pragma unroll
                for (int n = 0; n < 2; ++n) {
                    acc[m][n] = __builtin_amdgcn_mfma_f32_16x16x32_bf16(ah[m], bh[n], acc[m][n], 0, 0, 0);
                    acc[m][n] = __builtin_amdgcn_mfma_f32_16x16x32_bf16(al[m], bh[n], acc[m][n], 0, 0, 0);
                    acc[m][n] = __builtin_amdgcn_mfma_f32_16x16x32_bf16(ah[m], bl[n], acc[m][n], 0, 0, 0);
                }
        }
        __syncthreads();    // all reads done before next stage overwrites
    }

    // Epilogue: C/D layout col=lane&15, row=(lane>>4)*4+reg  [m89/m91]
#pragma unroll
    for (int m = 0; m < 4; ++m)
#pragma unroll
        for (int n = 0; n < 2; ++n) {
            const int col = bn + wn * 32 + n * 16 + lr;
            const int r0  = bm + wm * 64 + m * 16 + lg * 4;
#pragma unroll
            for (int j = 0; j < 4; ++j)
                C[(size_t)(r0 + j) * N + col] = acc[m][n][j];
        }
}

// ---------------- fallback f32 GEMM (if ws too small) ----------------
#define GM_BM 128
#define GM_BN 64
#define GM_BK 16
#define GM_TM 8
#define GM_TN 4

__global__ __launch_bounds__(256) void gemm_qproj(const float* __restrict__ A,
                                                  const float* __restrict__ B,
                                                  float* __restrict__ C,
                                                  int M, int N, int K) {
    __shared__ float As[GM_BK][GM_BM];
    __shared__ float Bs[GM_BK][GM_BN];
    const int tid = threadIdx.x;
    const int tx = tid & 15;
    const int ty = tid >> 4;
    const int bm = blockIdx.x * GM_BM;
    const int bn = blockIdx.y * GM_BN;
    float acc[GM_TM][GM_TN];
#pragma unroll
    for (int i = 0; i < GM_TM; ++i)
#pragma unroll
        for (int j = 0; j < GM_TN; ++j) acc[i][j] = 0.f;
    for (int k0 = 0; k0 < K; k0 += GM_BK) {
#pragma unroll
        for (int i = 0; i < 2; ++i) {
            int idx = tid * 2 + i;
            int row = idx >> 2;
            int c4  = idx & 3;
            float4 v = *(const float4*)(A + (size_t)(bm + row) * K + k0 + c4 * 4);
            As[c4 * 4 + 0][row] = v.x;
            As[c4 * 4 + 1][row] = v.y;
            As[c4 * 4 + 2][row] = v.z;
            As[c4 * 4 + 3][row] = v.w;
        }
        {
            int row = tid >> 4;
            int c4  = tid & 15;
            float4 v = *(const float4*)(B + (size_t)(k0 + row) * N + bn + c4 * 4);
            *(float4*)&Bs[row][c4 * 4] = v;
        }
        __syncthreads();
#pragma unroll
        for (int k = 0; k < GM_BK; ++k) {
            float a[GM_TM], b[GM_TN];
#pragma unroll
            for (int i = 0; i < GM_TM; ++i) a[i] = As[k][ty * GM_TM + i];
#pragma unroll
            for (int j = 0; j < GM_TN; ++j) b[j] = Bs[k][tx * GM_TN + j];
#pragma unroll
            for (int i = 0; i < GM_TM; ++i)
#pragma unroll
                for (int j = 0; j < GM_TN; ++j) acc[i][j] += a[i] * b[j];
        }
        __syncthreads();
    }
#pragma unroll
    for (int i = 0; i < GM_TM; ++i) {
        float4 v;
        v.x = acc[i][0]; v.y = acc[i][1]; v.z = acc[i][2]; v.w = acc[i][3];
        *(float4*)(C + (size_t)(bm + ty * GM_TM + i) * N + bn + tx * GM_TN) = v;
    }
}

// ---------------- fused gather / score / softmax / output ----------------
__global__ __launch_bounds__(256) void attn_fused(const float* __restrict__ qproj,
                                                  const int* __restrict__ sws,
                                                  const float* __restrict__ w2v,
                                                  float* __restrict__ out) {
    const int wave = threadIdx.x >> 6;
    const int lane = threadIdx.x & 63;
    const size_t row = (size_t)blockIdx.x * 4 + wave;

    const float4* q4 = (const float4*)(qproj + row * 768);
    float4 q[3];
#pragma unroll
    for (int j = 0; j < 3; ++j) q[j] = q4[j * 64 + lane];

    float4 ks[8][3];
    float dot[8];
#pragma unroll
    for (int k = 0; k < 8; ++k) {
        int id = sws[row * 8 + k];
        const float4* kp = (const float4*)(w2v + (size_t)id * 768);
        float d = 0.f;
#pragma unroll
        for (int j = 0; j < 3; ++j) {
            float4 v = kp[j * 64 + lane];
            ks[k][j] = v;
            d += q[j].x * v.x;
            d += q[j].y * v.y;
            d += q[j].z * v.z;
            d += q[j].w * v.w;
        }
        dot[k] = d;
    }
#pragma unroll
    for (int k = 0; k < 8; ++k) {
        float d = dot[k];
#pragma unroll
        for (int m = 1; m < 64; m <<= 1) d += __shfl_xor(d, m);
        dot[k] = d;
    }
    float mx = dot[0];
#pragma unroll
    for (int k = 1; k < 8; ++k) mx = fmaxf(mx, dot[k]);
    float w[8];
    float s = 0.f;
#pragma unroll
    for (int k = 0; k < 8; ++k) { w[k] = __expf(dot[k] - mx); s += w[k]; }
    const float inv = 1.f / s;

    float4 o[3];
#pragma unroll
    for (int j = 0; j < 3; ++j) { o[j].x = 0.f; o[j].y = 0.f; o[j].z = 0.f; o[j].w = 0.f; }
#pragma unroll
    for (int k = 0; k < 8; ++k) {
        const float a = w[k] * inv;
#pragma unroll
        for (int j = 0; j < 3; ++j) {
            o[j].x += a * ks[k][j].x;
            o[j].y += a * ks[k][j].y;
            o[j].z += a * ks[k][j].z;
            o[j].w += a * ks[k][j].w;
        }
    }
    float4* o4 = (float4*)(out + row * 768);
#pragma unroll
    for (int j = 0; j < 3; ++j) o4[j * 64 + lane] = o[j];
}

extern "C" void kernel_launch(void* const* d_in, const int* in_sizes, int n_in,
                              void* d_out, int out_size, void* d_ws, size_t ws_size,
                              hipStream_t stream) {
    const float* hidden = (const float*)d_in[0];
    const int*   sws    = (const int*)d_in[1];
    const float* w2v    = (const float*)d_in[2];
    const float* weight = (const float*)d_in[3];
    float*       out    = (float*)d_out;

    const int E = 768;
    const int M = in_sizes[0] / E;            // 8192
    float* qproj = out;                        // staged through d_out

    const size_t szA = (size_t)M * E * sizeof(unsigned short);
    const size_t szB = (size_t)E * E * sizeof(unsigned short);
    const size_t need = 2 * szA + 2 * szB;

    if (ws_size >= need) {
        unsigned short* Ahi  = (unsigned short*)d_ws;
        unsigned short* Alo  = Ahi + (size_t)M * E;
        unsigned short* BhiT = Alo + (size_t)M * E;
        unsigned short* BloT = BhiT + (size_t)E * E;

        split_bf16<<<2048, 256, 0, stream>>>((const float4*)hidden,
                                             (ushort4*)Ahi, (ushort4*)Alo,
                                             M * E / 4);
        split_bf16_T<<<dim3(E / 32, E / 32), 256, 0, stream>>>(weight, BhiT, BloT, E, E);

        dim3 ggrid((M / BM) * (E / BN));      // 768 blocks, %8==0
        gemm_mfma_glds<<<ggrid, 256, 0, stream>>>(Ahi, Alo, BhiT, BloT, qproj, M, E, E);
    } else {
        dim3 ggrid(M / GM_BM, E / GM_BN);
        gemm_qproj<<<ggrid, 256, 0, stream>>>(hidden, weight, qproj, M, E, E);
    }

    attn_fused<<<dim3(M / 4), 256, 0, stream>>>(qproj, sws, w2v, out);
}

// Round 4
// 81.250 us; speedup vs baseline: 2.2213x; 1.0242x over previous
//
#include <hip/hip_runtime.h>
#include <hip/hip_bf16.h>

// Problem: B=32, L=256, K=8, E=768, V=50000 ; M = B*L = 8192
// inputs: hidden [M,E] f32, similar_words [M,K] int32, word2vec [V,E] f32, weight [E,E] f32
// out:    [M,E] f32
//
// qproj = hidden @ weight via split-bf16 (hi/lo) MFMA, global_load_lds staging
// (m97 structure) + source-side swizzle (rule 21). 8 waves/block (512 thr) to
// double waves/CU: grid is 768 blocks = 3 blocks/CU exactly, so occupancy is
// grid-limited -> more waves per block is the only TLP lever.
// Then fused gather/softmax/weighted-sum. qproj staged through d_out.

typedef __attribute__((ext_vector_type(8))) short bf16x8;   // 8 bf16 = 4 VGPRs
typedef __attribute__((ext_vector_type(4))) float f32x4;

__device__ __forceinline__ unsigned short f2bf(float f) {   // RNE f32 -> bf16
    unsigned int u = __float_as_uint(f);
    u += 0x7FFFu + ((u >> 16) & 1u);
    return (unsigned short)(u >> 16);
}
__device__ __forceinline__ float bf2f(unsigned short h) {
    return __uint_as_float(((unsigned int)h) << 16);
}

// async global->LDS, 16B per lane; LDS dest = wave-uniform base + lane*16.
__device__ __forceinline__ void gload16(const void* g, void* l) {
    __builtin_amdgcn_global_load_lds(
        (const __attribute__((address_space(1))) unsigned int*)g,
        (__attribute__((address_space(3))) unsigned int*)l, 16, 0, 0);
}

// ---------------- fused conversion pre-pass ----------------
// blocks [0, ablocks): hidden f32 -> Ahi/Alo bf16 (grid-stride over float4s)
// blocks [ablocks, ..): weight [K][N] f32 -> BhiT/BloT bf16 [N][K] (32x32 tiles)
__global__ __launch_bounds__(256) void split_all(const float4* __restrict__ x,
                                                 ushort4* __restrict__ hi,
                                                 ushort4* __restrict__ lo, int n4,
                                                 const float* __restrict__ W,
                                                 unsigned short* __restrict__ hiT,
                                                 unsigned short* __restrict__ loT,
                                                 int K, int N, int ablocks) {
    __shared__ float tile[32][33];
    if ((int)blockIdx.x < ablocks) {
        int i = blockIdx.x * 256 + threadIdx.x;
        const int stride = ablocks * 256;
        for (; i < n4; i += stride) {
            float4 v = x[i];
            ushort4 h, l;
            h.x = f2bf(v.x); l.x = f2bf(v.x - bf2f(h.x));
            h.y = f2bf(v.y); l.y = f2bf(v.y - bf2f(h.y));
            h.z = f2bf(v.z); l.z = f2bf(v.z - bf2f(h.z));
            h.w = f2bf(v.w); l.w = f2bf(v.w - bf2f(h.w));
            hi[i] = h; lo[i] = l;
        }
    } else {
        const int bid = blockIdx.x - ablocks;
        const int nbk = K / 32;
        const int bk = (bid % nbk) * 32, bn = (bid / nbk) * 32;
        const int tx = threadIdx.x & 31, ty = threadIdx.x >> 5;
#pragma unroll
        for (int r = ty; r < 32; r += 8)
            tile[r][tx] = W[(size_t)(bk + r) * N + bn + tx];
        __syncthreads();
#pragma unroll
        for (int r = ty; r < 32; r += 8) {
            float v = tile[tx][r];                 // = W[bk+tx][bn+r]
            unsigned short h = f2bf(v);
            size_t o = (size_t)(bn + r) * K + bk + tx;
            hiT[o] = h;
            loT[o] = f2bf(v - bf2f(h));
        }
    }
}

// ---------------- split-bf16 MFMA GEMM, global_load_lds staging ----------------
// C[M][N] = A[M][K]*B[K][N]; A as Ahi/Alo [M][K], B as BhiT/BloT [N][K].
// Tile 128x64, BK=64 (8 chunks of 8 bf16), 8 waves (4x2), wave = 2x2 16x16 frags.
// LDS 16B-slot regions: AHI[128*8] @0, ALO @1024, BHI[64*8] @2048, BLO @2560.
// Slot map: slot = row*8 + (kc ^ (row&7)); written linearly by gload_lds with
// the inverse swizzle applied to the per-lane GLOBAL address (rule 21).

#define BM 128
#define BN 64
#define BK 64

__global__ __launch_bounds__(512, 6) void gemm_mfma_glds(
        const unsigned short* __restrict__ Ahi, const unsigned short* __restrict__ Alo,
        const unsigned short* __restrict__ BhiT, const unsigned short* __restrict__ BloT,
        float* __restrict__ C, int M, int N, int K) {

    // XCD-aware swizzle (nwg=768, %8==0): 12 tiles sharing an A-panel -> one XCD L2.
    const int nwg = gridDim.x;
    const int per = nwg >> 3;
    const int l   = (blockIdx.x & 7) * per + (blockIdx.x >> 3);
    const int nbn = N / BN;
    const int bm  = (l / nbn) * BM;
    const int bn  = (l % nbn) * BN;

    __shared__ unsigned short lds[3072 * 8];   // 48 KiB

    const int tid  = threadIdx.x;
    const int lane = tid & 63;
    const int w    = tid >> 6;                  // wave 0..7
    const int lr   = lane & 15, lg = lane >> 4;
    const int wm   = w >> 1, wn = w & 1;        // 4 x 2 wave grid

    const int lane8 = lane >> 3;                // 0..7
    const int kcl   = (lane & 7) ^ lane8;       // staging: this lane's kc (pre-swizzle)

    f32x4 acc[2][2];
#pragma unroll
    for (int m = 0; m < 2; ++m)
#pragma unroll
        for (int n = 0; n < 2; ++n) acc[m][n] = (f32x4){0.f, 0.f, 0.f, 0.f};

    const int niter = K / BK;
    for (int it = 0; it < niter; ++it) {
        const int k0 = it * BK;

        // ---- stage tile via global_load_lds (6 issues/wave) ----
#pragma unroll
        for (int i = 0; i < 2; ++i) {
            size_t g = (size_t)(bm + 16 * w + 8 * i + lane8) * K + k0 + kcl * 8;
            gload16(Ahi + g, &lds[(size_t)(       128 * w + 64 * i) * 8]);
            gload16(Alo + g, &lds[(size_t)(1024 + 128 * w + 64 * i) * 8]);
        }
        {
            size_t g = (size_t)(bn + 8 * w + lane8) * K + k0 + kcl * 8;
            gload16(BhiT + g, &lds[(size_t)(2048 + 64 * w) * 8]);
            gload16(BloT + g, &lds[(size_t)(2560 + 64 * w) * 8]);
        }
        __syncthreads();    // implicit vmcnt(0) drain -> LDS ready

        // ---- compute: 2 K-slices x (8 ds_read_b128 + 12 MFMA) ----
#pragma unroll
        for (int ks = 0; ks < 2; ++ks) {
            const int kc = ks * 4 + lg;
            const int kx = kc ^ (lr & 7);       // row&7 == lr&7 for all frag rows
            bf16x8 ah[2], al[2], bh[2], bl[2];
#pragma unroll
            for (int m = 0; m < 2; ++m) {
                int slot = (wm * 32 + m * 16 + lr) * 8 + kx;
                ah[m] = *(const bf16x8*)&lds[(size_t)slot * 8];
                al[m] = *(const bf16x8*)&lds[(size_t)(1024 + slot) * 8];
            }
#pragma unroll
            for (int n = 0; n < 2; ++n) {
                int slot = (wn * 32 + n * 16 + lr) * 8 + kx;
                bh[n] = *(const bf16x8*)&lds[(size_t)(2048 + slot) * 8];
                bl[n] = *(const bf16x8*)&lds[(size_t)(2560 + slot) * 8];
            }
#pragma unroll
            for (int m = 0; m < 2; ++m)
#pragma unroll
                for (int n = 0; n < 2; ++n) {
                    acc[m][n] = __builtin_amdgcn_mfma_f32_16x16x32_bf16(ah[m], bh[n], acc[m][n], 0, 0, 0);
                    acc[m][n] = __builtin_amdgcn_mfma_f32_16x16x32_bf16(al[m], bh[n], acc[m][n], 0, 0, 0);
                    acc[m][n] = __builtin_amdgcn_mfma_f32_16x16x32_bf16(ah[m], bl[n], acc[m][n], 0, 0, 0);
                }
        }
        __syncthreads();    // all reads done before next stage overwrites
    }

    // Epilogue: C/D layout col=lane&15, row=(lane>>4)*4+reg  [m89/m91]
#pragma unroll
    for (int m = 0; m < 2; ++m)
#pragma unroll
        for (int n = 0; n < 2; ++n) {
            const int col = bn + wn * 32 + n * 16 + lr;
            const int r0  = bm + wm * 32 + m * 16 + lg * 4;
#pragma unroll
            for (int j = 0; j < 4; ++j)
                C[(size_t)(r0 + j) * N + col] = acc[m][n][j];
        }
}

// ---------------- fallback f32 GEMM (if ws too small) ----------------
#define GM_BM 128
#define GM_BN 64
#define GM_BK 16
#define GM_TM 8
#define GM_TN 4

__global__ __launch_bounds__(256) void gemm_qproj(const float* __restrict__ A,
                                                  const float* __restrict__ B,
                                                  float* __restrict__ C,
                                                  int M, int N, int K) {
    __shared__ float As[GM_BK][GM_BM];
    __shared__ float Bs[GM_BK][GM_BN];
    const int tid = threadIdx.x;
    const int tx = tid & 15;
    const int ty = tid >> 4;
    const int bm = blockIdx.x * GM_BM;
    const int bn = blockIdx.y * GM_BN;
    float acc[GM_TM][GM_TN];
#pragma unroll
    for (int i = 0; i < GM_TM; ++i)
#pragma unroll
        for (int j = 0; j < GM_TN; ++j) acc[i][j] = 0.f;
    for (int k0 = 0; k0 < K; k0 += GM_BK) {
#pragma unroll
        for (int i = 0; i < 2; ++i) {
            int idx = tid * 2 + i;
            int row = idx >> 2;
            int c4  = idx & 3;
            float4 v = *(const float4*)(A + (size_t)(bm + row) * K + k0 + c4 * 4);
            As[c4 * 4 + 0][row] = v.x;
            As[c4 * 4 + 1][row] = v.y;
            As[c4 * 4 + 2][row] = v.z;
            As[c4 * 4 + 3][row] = v.w;
        }
        {
            int row = tid >> 4;
            int c4  = tid & 15;
            float4 v = *(const float4*)(B + (size_t)(k0 + row) * N + bn + c4 * 4);
            *(float4*)&Bs[row][c4 * 4] = v;
        }
        __syncthreads();
#pragma unroll
        for (int k = 0; k < GM_BK; ++k) {
            float a[GM_TM], b[GM_TN];
#pragma unroll
            for (int i = 0; i < GM_TM; ++i) a[i] = As[k][ty * GM_TM + i];
#pragma unroll
            for (int j = 0; j < GM_TN; ++j) b[j] = Bs[k][tx * GM_TN + j];
#pragma unroll
            for (int i = 0; i < GM_TM; ++i)
#pragma unroll
                for (int j = 0; j < GM_TN; ++j) acc[i][j] += a[i] * b[j];
        }
        __syncthreads();
    }
#pragma unroll
    for (int i = 0; i < GM_TM; ++i) {
        float4 v;
        v.x = acc[i][0]; v.y = acc[i][1]; v.z = acc[i][2]; v.w = acc[i][3];
        *(float4*)(C + (size_t)(bm + ty * GM_TM + i) * N + bn + tx * GM_TN) = v;
    }
}

// ---------------- fused gather / score / softmax / output ----------------
__global__ __launch_bounds__(256) void attn_fused(const float* __restrict__ qproj,
                                                  const int* __restrict__ sws,
                                                  const float* __restrict__ w2v,
                                                  float* __restrict__ out) {
    const int wave = threadIdx.x >> 6;
    const int lane = threadIdx.x & 63;
    const size_t row = (size_t)blockIdx.x * 4 + wave;

    const float4* q4 = (const float4*)(qproj + row * 768);
    float4 q[3];
#pragma unroll
    for (int j = 0; j < 3; ++j) q[j] = q4[j * 64 + lane];

    float4 ks[8][3];
    float dot[8];
#pragma unroll
    for (int k = 0; k < 8; ++k) {
        int id = sws[row * 8 + k];
        const float4* kp = (const float4*)(w2v + (size_t)id * 768);
        float d = 0.f;
#pragma unroll
        for (int j = 0; j < 3; ++j) {
            float4 v = kp[j * 64 + lane];
            ks[k][j] = v;
            d += q[j].x * v.x;
            d += q[j].y * v.y;
            d += q[j].z * v.z;
            d += q[j].w * v.w;
        }
        dot[k] = d;
    }
#pragma unroll
    for (int k = 0; k < 8; ++k) {
        float d = dot[k];
#pragma unroll
        for (int m = 1; m < 64; m <<= 1) d += __shfl_xor(d, m);
        dot[k] = d;
    }
    float mx = dot[0];
#pragma unroll
    for (int k = 1; k < 8; ++k) mx = fmaxf(mx, dot[k]);
    float w[8];
    float s = 0.f;
#pragma unroll
    for (int k = 0; k < 8; ++k) { w[k] = __expf(dot[k] - mx); s += w[k]; }
    const float inv = 1.f / s;

    float4 o[3];
#pragma unroll
    for (int j = 0; j < 3; ++j) { o[j].x = 0.f; o[j].y = 0.f; o[j].z = 0.f; o[j].w = 0.f; }
#pragma unroll
    for (int k = 0; k < 8; ++k) {
        const float a = w[k] * inv;
#pragma unroll
        for (int j = 0; j < 3; ++j) {
            o[j].x += a * ks[k][j].x;
            o[j].y += a * ks[k][j].y;
            o[j].z += a * ks[k][j].z;
            o[j].w += a * ks[k][j].w;
        }
    }
    float4* o4 = (float4*)(out + row * 768);
#pragma unroll
    for (int j = 0; j < 3; ++j) o4[j * 64 + lane] = o[j];
}

extern "C" void kernel_launch(void* const* d_in, const int* in_sizes, int n_in,
                              void* d_out, int out_size, void* d_ws, size_t ws_size,
                              hipStream_t stream) {
    const float* hidden = (const float*)d_in[0];
    const int*   sws    = (const int*)d_in[1];
    const float* w2v    = (const float*)d_in[2];
    const float* weight = (const float*)d_in[3];
    float*       out    = (float*)d_out;

    const int E = 768;
    const int M = in_sizes[0] / E;            // 8192
    float* qproj = out;                        // staged through d_out

    const size_t szA = (size_t)M * E * sizeof(unsigned short);
    const size_t szB = (size_t)E * E * sizeof(unsigned short);
    const size_t need = 2 * szA + 2 * szB;

    if (ws_size >= need) {
        unsigned short* Ahi  = (unsigned short*)d_ws;
        unsigned short* Alo  = Ahi + (size_t)M * E;
        unsigned short* BhiT = Alo + (size_t)M * E;
        unsigned short* BloT = BhiT + (size_t)E * E;

        const int ablocks = 2048;
        const int wblocks = (E / 32) * (E / 32);   // 576
        split_all<<<ablocks + wblocks, 256, 0, stream>>>(
            (const float4*)hidden, (ushort4*)Ahi, (ushort4*)Alo, M * E / 4,
            weight, BhiT, BloT, E, E, ablocks);

        dim3 ggrid((M / BM) * (E / BN));      // 768 blocks, %8==0
        gemm_mfma_glds<<<ggrid, 512, 0, stream>>>(Ahi, Alo, BhiT, BloT, qproj, M, E, E);
    } else {
        dim3 ggrid(M / GM_BM, E / GM_BN);
        gemm_qproj<<<ggrid, 256, 0, stream>>>(hidden, weight, qproj, M, E, E);
    }

    attn_fused<<<dim3(M / 4), 256, 0, stream>>>(qproj, sws, w2v, out);
}

// Round 5
// 64.983 us; speedup vs baseline: 2.7774x; 1.2503x over previous
//
#include <hip/hip_runtime.h>
#include <hip/hip_bf16.h>

// Problem: B=32, L=256, K=8, E=768, V=50000 ; M = B*L = 8192
// inputs: hidden [M,E] f32, similar_words [M,K] int32, word2vec [V,E] f32, weight [E,E] f32
// out:    [M,E] f32
//
// qproj = hidden @ weight via SINGLE f16 MFMA (f16 rel-err 2^-11 -> logit noise
// ~0.011 vs logit spread ~28; threshold 0.108 is bf16-grade). 3x less MFMA/LDS/
// staging work than the round-2..4 hi/lo bf16 split. global_load_lds staging
// (m97 structure) + source-side swizzle (rule 21, 0 conflicts measured r2).
// Then fused gather/softmax/weighted-sum. qproj staged through d_out.
// HEDGE: if absmax > 0.108, revert to 3-MFMA bf16 split next round.

typedef __attribute__((ext_vector_type(8))) _Float16 f16x8;   // 8 f16 = 4 VGPRs
typedef __attribute__((ext_vector_type(4))) float f32x4;

__device__ __forceinline__ unsigned short f2h(float f) {   // RNE f32 -> f16
    _Float16 h = (_Float16)f;
    return __builtin_bit_cast(unsigned short, h);
}

// async global->LDS, 16B per lane; LDS dest = wave-uniform base + lane*16.
__device__ __forceinline__ void gload16(const void* g, void* l) {
    __builtin_amdgcn_global_load_lds(
        (const __attribute__((address_space(1))) unsigned int*)g,
        (__attribute__((address_space(3))) unsigned int*)l, 16, 0, 0);
}

// ---------------- fused conversion pre-pass ----------------
// blocks [0, ablocks): hidden f32 -> Af f16 (grid-stride over float4s)
// blocks [ablocks, ..): weight [K][N] f32 -> WfT f16 [N][K] (32x32 tiles)
__global__ __launch_bounds__(256) void split_all(const float4* __restrict__ x,
                                                 ushort4* __restrict__ hf, int n4,
                                                 const float* __restrict__ W,
                                                 unsigned short* __restrict__ WfT,
                                                 int K, int N, int ablocks) {
    __shared__ float tile[32][33];
    if ((int)blockIdx.x < ablocks) {
        int i = blockIdx.x * 256 + threadIdx.x;
        const int stride = ablocks * 256;
        for (; i < n4; i += stride) {
            float4 v = x[i];
            ushort4 h;
            h.x = f2h(v.x); h.y = f2h(v.y); h.z = f2h(v.z); h.w = f2h(v.w);
            hf[i] = h;
        }
    } else {
        const int bid = blockIdx.x - ablocks;
        const int nbk = K / 32;
        const int bk = (bid % nbk) * 32, bn = (bid / nbk) * 32;
        const int tx = threadIdx.x & 31, ty = threadIdx.x >> 5;
#pragma unroll
        for (int r = ty; r < 32; r += 8)
            tile[r][tx] = W[(size_t)(bk + r) * N + bn + tx];
        __syncthreads();
#pragma unroll
        for (int r = ty; r < 32; r += 8) {
            float v = tile[tx][r];                 // = W[bk+tx][bn+r]
            WfT[(size_t)(bn + r) * K + bk + tx] = f2h(v);
        }
    }
}

// ---------------- f16 MFMA GEMM, global_load_lds staging ----------------
// C[M][N] = A[M][K]*B[K][N]; A as Af [M][K] f16, B as BfT [N][K] f16.
// Tile 128x64, BK=64 (8 chunks of 8 f16), 8 waves (4x2), wave = 2x2 16x16 frags.
// LDS 16B-slot regions: AF[128*8] @0, BF[64*8] @1024.
// Slot map: slot = row*8 + (kc ^ (row&7)); written linearly by gload_lds with
// the inverse swizzle applied to the per-lane GLOBAL address (rule 21).

#define BM 128
#define BN 64
#define BK 64

__global__ __launch_bounds__(512, 6) void gemm_mfma_f16(
        const unsigned short* __restrict__ Af, const unsigned short* __restrict__ BfT,
        float* __restrict__ C, int M, int N, int K) {

    // XCD-aware swizzle (nwg=768, %8==0): 12 tiles sharing an A-panel -> one XCD L2.
    const int nwg = gridDim.x;
    const int per = nwg >> 3;
    const int l   = (blockIdx.x & 7) * per + (blockIdx.x >> 3);
    const int nbn = N / BN;
    const int bm  = (l / nbn) * BM;
    const int bn  = (l % nbn) * BN;

    __shared__ unsigned short lds[1536 * 8];   // 24 KiB: A 1024 slots, B 512 slots
    const int BOFF = 1024;

    const int tid  = threadIdx.x;
    const int lane = tid & 63;
    const int w    = tid >> 6;                  // wave 0..7
    const int lr   = lane & 15, lg = lane >> 4;
    const int wm   = w >> 1, wn = w & 1;        // 4 x 2 wave grid

    const int lane8 = lane >> 3;                // 0..7
    const int kcl   = (lane & 7) ^ lane8;       // staging: this lane's kc (pre-swizzle)

    f32x4 acc[2][2];
#pragma unroll
    for (int m = 0; m < 2; ++m)
#pragma unroll
        for (int n = 0; n < 2; ++n) acc[m][n] = (f32x4){0.f, 0.f, 0.f, 0.f};

    const int niter = K / BK;
    for (int it = 0; it < niter; ++it) {
        const int k0 = it * BK;

        // ---- stage tile via global_load_lds (3 issues/wave) ----
#pragma unroll
        for (int i = 0; i < 2; ++i) {
            size_t g = (size_t)(bm + 16 * w + 8 * i + lane8) * K + k0 + kcl * 8;
            gload16(Af + g, &lds[(size_t)(128 * w + 64 * i) * 8]);
        }
        {
            size_t g = (size_t)(bn + 8 * w + lane8) * K + k0 + kcl * 8;
            gload16(BfT + g, &lds[(size_t)(BOFF + 64 * w) * 8]);
        }
        __syncthreads();    // implicit vmcnt(0) drain -> LDS ready

        // ---- compute: 2 K-slices x (4 ds_read_b128 + 4 MFMA) ----
#pragma unroll
        for (int ks = 0; ks < 2; ++ks) {
            const int kc = ks * 4 + lg;
            const int kx = kc ^ (lr & 7);       // row&7 == lr&7 for all frag rows
            f16x8 a[2], b[2];
#pragma unroll
            for (int m = 0; m < 2; ++m) {
                int slot = (wm * 32 + m * 16 + lr) * 8 + kx;
                a[m] = *(const f16x8*)&lds[(size_t)slot * 8];
            }
#pragma unroll
            for (int n = 0; n < 2; ++n) {
                int slot = (wn * 32 + n * 16 + lr) * 8 + kx;
                b[n] = *(const f16x8*)&lds[(size_t)(BOFF + slot) * 8];
            }
#pragma unroll
            for (int m = 0; m < 2; ++m)
#pragma unroll
                for (int n = 0; n < 2; ++n)
                    acc[m][n] = __builtin_amdgcn_mfma_f32_16x16x32_f16(a[m], b[n], acc[m][n], 0, 0, 0);
        }
        __syncthreads();    // all reads done before next stage overwrites
    }

    // Epilogue: C/D layout col=lane&15, row=(lane>>4)*4+reg  [m89/m91]
#pragma unroll
    for (int m = 0; m < 2; ++m)
#pragma unroll
        for (int n = 0; n < 2; ++n) {
            const int col = bn + wn * 32 + n * 16 + lr;
            const int r0  = bm + wm * 32 + m * 16 + lg * 4;
#pragma unroll
            for (int j = 0; j < 4; ++j)
                C[(size_t)(r0 + j) * N + col] = acc[m][n][j];
        }
}

// ---------------- fallback f32 GEMM (if ws too small) ----------------
#define GM_BM 128
#define GM_BN 64
#define GM_BK 16
#define GM_TM 8
#define GM_TN 4

__global__ __launch_bounds__(256) void gemm_qproj(const float* __restrict__ A,
                                                  const float* __restrict__ B,
                                                  float* __restrict__ C,
                                                  int M, int N, int K) {
    __shared__ float As[GM_BK][GM_BM];
    __shared__ float Bs[GM_BK][GM_BN];
    const int tid = threadIdx.x;
    const int tx = tid & 15;
    const int ty = tid >> 4;
    const int bm = blockIdx.x * GM_BM;
    const int bn = blockIdx.y * GM_BN;
    float acc[GM_TM][GM_TN];
#pragma unroll
    for (int i = 0; i < GM_TM; ++i)
#pragma unroll
        for (int j = 0; j < GM_TN; ++j) acc[i][j] = 0.f;
    for (int k0 = 0; k0 < K; k0 += GM_BK) {
#pragma unroll
        for (int i = 0; i < 2; ++i) {
            int idx = tid * 2 + i;
            int row = idx >> 2;
            int c4  = idx & 3;
            float4 v = *(const float4*)(A + (size_t)(bm + row) * K + k0 + c4 * 4);
            As[c4 * 4 + 0][row] = v.x;
            As[c4 * 4 + 1][row] = v.y;
            As[c4 * 4 + 2][row] = v.z;
            As[c4 * 4 + 3][row] = v.w;
        }
        {
            int row = tid >> 4;
            int c4  = tid & 15;
            float4 v = *(const float4*)(B + (size_t)(k0 + row) * N + bn + c4 * 4);
            *(float4*)&Bs[row][c4 * 4] = v;
        }
        __syncthreads();
#pragma unroll
        for (int k = 0; k < GM_BK; ++k) {
            float a[GM_TM], b[GM_TN];
#pragma unroll
            for (int i = 0; i < GM_TM; ++i) a[i] = As[k][ty * GM_TM + i];
#pragma unroll
            for (int j = 0; j < GM_TN; ++j) b[j] = Bs[k][tx * GM_TN + j];
#pragma unroll
            for (int i = 0; i < GM_TM; ++i)
#pragma unroll
                for (int j = 0; j < GM_TN; ++j) acc[i][j] += a[i] * b[j];
        }
        __syncthreads();
    }
#pragma unroll
    for (int i = 0; i < GM_TM; ++i) {
        float4 v;
        v.x = acc[i][0]; v.y = acc[i][1]; v.z = acc[i][2]; v.w = acc[i][3];
        *(float4*)(C + (size_t)(bm + ty * GM_TM + i) * N + bn + tx * GM_TN) = v;
    }
}

// ---------------- fused gather / score / softmax / output ----------------
__global__ __launch_bounds__(256) void attn_fused(const float* __restrict__ qproj,
                                                  const int* __restrict__ sws,
                                                  const float* __restrict__ w2v,
                                                  float* __restrict__ out) {
    const int wave = threadIdx.x >> 6;
    const int lane = threadIdx.x & 63;
    const size_t row = (size_t)blockIdx.x * 4 + wave;

    const float4* q4 = (const float4*)(qproj + row * 768);
    float4 q[3];
#pragma unroll
    for (int j = 0; j < 3; ++j) q[j] = q4[j * 64 + lane];

    float4 ks[8][3];
    float dot[8];
#pragma unroll
    for (int k = 0; k < 8; ++k) {
        int id = sws[row * 8 + k];
        const float4* kp = (const float4*)(w2v + (size_t)id * 768);
        float d = 0.f;
#pragma unroll
        for (int j = 0; j < 3; ++j) {
            float4 v = kp[j * 64 + lane];
            ks[k][j] = v;
            d += q[j].x * v.x;
            d += q[j].y * v.y;
            d += q[j].z * v.z;
            d += q[j].w * v.w;
        }
        dot[k] = d;
    }
#pragma unroll
    for (int k = 0; k < 8; ++k) {
        float d = dot[k];
#pragma unroll
        for (int m = 1; m < 64; m <<= 1) d += __shfl_xor(d, m);
        dot[k] = d;
    }
    float mx = dot[0];
#pragma unroll
    for (int k = 1; k < 8; ++k) mx = fmaxf(mx, dot[k]);
    float w[8];
    float s = 0.f;
#pragma unroll
    for (int k = 0; k < 8; ++k) { w[k] = __expf(dot[k] - mx); s += w[k]; }
    const float inv = 1.f / s;

    float4 o[3];
#pragma unroll
    for (int j = 0; j < 3; ++j) { o[j].x = 0.f; o[j].y = 0.f; o[j].z = 0.f; o[j].w = 0.f; }
#pragma unroll
    for (int k = 0; k < 8; ++k) {
        const float a = w[k] * inv;
#pragma unroll
        for (int j = 0; j < 3; ++j) {
            o[j].x += a * ks[k][j].x;
            o[j].y += a * ks[k][j].y;
            o[j].z += a * ks[k][j].z;
            o[j].w += a * ks[k][j].w;
        }
    }
    float4* o4 = (float4*)(out + row * 768);
#pragma unroll
    for (int j = 0; j < 3; ++j) o4[j * 64 + lane] = o[j];
}

extern "C" void kernel_launch(void* const* d_in, const int* in_sizes, int n_in,
                              void* d_out, int out_size, void* d_ws, size_t ws_size,
                              hipStream_t stream) {
    const float* hidden = (const float*)d_in[0];
    const int*   sws    = (const int*)d_in[1];
    const float* w2v    = (const float*)d_in[2];
    const float* weight = (const float*)d_in[3];
    float*       out    = (float*)d_out;

    const int E = 768;
    const int M = in_sizes[0] / E;            // 8192
    float* qproj = out;                        // staged through d_out

    const size_t szA = (size_t)M * E * sizeof(unsigned short);   // 12.6 MB
    const size_t szB = (size_t)E * E * sizeof(unsigned short);   // 1.2 MB
    const size_t need = szA + szB;

    if (ws_size >= need) {
        unsigned short* Af  = (unsigned short*)d_ws;
        unsigned short* WfT = Af + (size_t)M * E;

        const int ablocks = 2048;
        const int wblocks = (E / 32) * (E / 32);   // 576
        split_all<<<ablocks + wblocks, 256, 0, stream>>>(
            (const float4*)hidden, (ushort4*)Af, M * E / 4,
            weight, WfT, E, E, ablocks);

        dim3 ggrid((M / BM) * (E / BN));      // 768 blocks, %8==0
        gemm_mfma_f16<<<ggrid, 512, 0, stream>>>(Af, WfT, qproj, M, E, E);
    } else {
        dim3 ggrid(M / GM_BM, E / GM_BN);
        gemm_qproj<<<ggrid, 256, 0, stream>>>(hidden, weight, qproj, M, E, E);
    }

    attn_fused<<<dim3(M / 4), 256, 0, stream>>>(qproj, sws, w2v, out);
}

// Round 6
// 63.618 us; speedup vs baseline: 2.8370x; 1.0215x over previous
//
#include <hip/hip_runtime.h>
#include <hip/hip_bf16.h>

// Problem: B=32, L=256, K=8, E=768, V=50000 ; M = B*L = 8192
// inputs: hidden [M,E] f32, similar_words [M,K] int32, word2vec [V,E] f32, weight [E,E] f32
// out:    [M,E] f32
//
// Pipeline: split_all (hidden->f16, W->W^T f16)  ->  f16 MFMA GEMM (qproj f16
// in d_ws, double-buffered LDS, stage-early 2-phase, global_load_lds +
// source-side swizzle)  ->  fused gather/softmax/weighted-sum (f16 qproj).
// Error budget: f16 qproj + f16 GEMM -> absmax ~0.05 vs threshold 0.108.

typedef __attribute__((ext_vector_type(8))) _Float16 f16x8;   // 8 f16 = 4 VGPRs
typedef __attribute__((ext_vector_type(4))) float f32x4;

__device__ __forceinline__ unsigned short f2h(float f) {   // RNE f32 -> f16
    _Float16 h = (_Float16)f;
    return __builtin_bit_cast(unsigned short, h);
}
__device__ __forceinline__ float h2f(unsigned short u) {
    return (float)__builtin_bit_cast(_Float16, u);
}

// async global->LDS, 16B per lane; LDS dest = wave-uniform base + lane*16.
__device__ __forceinline__ void gload16(const void* g, void* l) {
    __builtin_amdgcn_global_load_lds(
        (const __attribute__((address_space(1))) unsigned int*)g,
        (__attribute__((address_space(3))) unsigned int*)l, 16, 0, 0);
}

// ---------------- fused conversion pre-pass ----------------
// blocks [0, ablocks): hidden f32 -> Af f16 (grid-stride over float4s)
// blocks [ablocks, ..): weight [K][N] f32 -> WfT f16 [N][K] (32x32 tiles)
__global__ __launch_bounds__(256) void split_all(const float4* __restrict__ x,
                                                 ushort4* __restrict__ hf, int n4,
                                                 const float* __restrict__ W,
                                                 unsigned short* __restrict__ WfT,
                                                 int K, int N, int ablocks) {
    __shared__ float tile[32][33];
    if ((int)blockIdx.x < ablocks) {
        int i = blockIdx.x * 256 + threadIdx.x;
        const int stride = ablocks * 256;
        for (; i < n4; i += stride) {
            float4 v = x[i];
            ushort4 h;
            h.x = f2h(v.x); h.y = f2h(v.y); h.z = f2h(v.z); h.w = f2h(v.w);
            hf[i] = h;
        }
    } else {
        const int bid = blockIdx.x - ablocks;
        const int nbk = K / 32;
        const int bk = (bid % nbk) * 32, bn = (bid / nbk) * 32;
        const int tx = threadIdx.x & 31, ty = threadIdx.x >> 5;
#pragma unroll
        for (int r = ty; r < 32; r += 8)
            tile[r][tx] = W[(size_t)(bk + r) * N + bn + tx];
        __syncthreads();
#pragma unroll
        for (int r = ty; r < 32; r += 8) {
            float v = tile[tx][r];                 // = W[bk+tx][bn+r]
            WfT[(size_t)(bn + r) * K + bk + tx] = f2h(v);
        }
    }
}

// ---------------- f16 MFMA GEMM, dbuf LDS + stage-early ----------------
// C[M][N] = A[M][K]*B[K][N]; A as Af [M][K] f16, B as BfT [N][K] f16; C f16.
// Tile 128x64, BK=64 (8 chunks of 8 f16), 4 waves (2x2), wave = 64x32 (4x2 frags).
// Per-buffer LDS 16B-slot regions: A[128*8] @0, B[64*8] @1024; two buffers.
// Slot map: slot = row*8 + (kc ^ (row&7)); written linearly by gload_lds with
// the inverse swizzle applied to the per-lane GLOBAL address (rule 21).

#define BM 128
#define BN 64
#define BK 64

__global__ __launch_bounds__(256) void gemm_mfma_f16(
        const unsigned short* __restrict__ Af, const unsigned short* __restrict__ BfT,
        unsigned short* __restrict__ C, int M, int N, int K) {

    // XCD-aware swizzle (nwg=768, %8==0): 12 tiles sharing an A-panel -> one XCD L2.
    const int nwg = gridDim.x;
    const int per = nwg >> 3;
    const int l   = (blockIdx.x & 7) * per + (blockIdx.x >> 3);
    const int nbn = N / BN;
    const int bm  = (l / nbn) * BM;
    const int bn  = (l % nbn) * BN;

    __shared__ unsigned short lds[2 * 1536 * 8];   // 48 KiB: 2 buffers
    const int BOFF = 1024;                          // B region within a buffer (slots)
    const int BUF  = 1536;                          // buffer stride (slots)

    const int tid  = threadIdx.x;
    const int lane = tid & 63;
    const int w    = tid >> 6;                  // wave 0..3
    const int lr   = lane & 15, lg = lane >> 4;
    const int wm   = w >> 1, wn = w & 1;        // 2 x 2 wave grid

    const int lane8 = lane >> 3;                // 0..7
    const int kcl   = (lane & 7) ^ lane8;       // staging: this lane's kc (pre-swizzle)

    f32x4 acc[4][2];
#pragma unroll
    for (int m = 0; m < 4; ++m)
#pragma unroll
        for (int n = 0; n < 2; ++n) acc[m][n] = (f32x4){0.f, 0.f, 0.f, 0.f};

    // Stage tile k0 into buffer `buf` (6 gloads/wave).
    auto STAGE = [&](int k0, int buf) {
#pragma unroll
        for (int i = 0; i < 4; ++i) {
            size_t g = (size_t)(bm + 32 * w + 8 * i + lane8) * K + k0 + kcl * 8;
            gload16(Af + g, &lds[(size_t)(buf * BUF + 256 * w + 64 * i) * 8]);
        }
#pragma unroll
        for (int i = 0; i < 2; ++i) {
            size_t g = (size_t)(bn + 16 * w + 8 * i + lane8) * K + k0 + kcl * 8;
            gload16(BfT + g, &lds[(size_t)(buf * BUF + BOFF + 128 * w + 64 * i) * 8]);
        }
    };

    const int niter = K / BK;                   // 12
    STAGE(0, 0);
    __syncthreads();                             // drain: buf0 ready

    int cur = 0;
    for (int it = 0; it < niter; ++it) {
        if (it + 1 < niter) STAGE((it + 1) * BK, cur ^ 1);   // issue-early: fly during compute

        const int base = cur * BUF;
#pragma unroll
        for (int ks = 0; ks < 2; ++ks) {
            const int kc = ks * 4 + lg;
            const int kx = kc ^ (lr & 7);       // row&7 == lr&7 for all frag rows
            f16x8 a[4], b[2];
#pragma unroll
            for (int m = 0; m < 4; ++m) {
                int slot = base + (wm * 64 + m * 16 + lr) * 8 + kx;
                a[m] = *(const f16x8*)&lds[(size_t)slot * 8];
            }
#pragma unroll
            for (int n = 0; n < 2; ++n) {
                int slot = base + BOFF + (wn * 32 + n * 16 + lr) * 8 + kx;
                b[n] = *(const f16x8*)&lds[(size_t)slot * 8];
            }
#pragma unroll
            for (int m = 0; m < 4; ++m)
#pragma unroll
                for (int n = 0; n < 2; ++n)
                    acc[m][n] = __builtin_amdgcn_mfma_f32_16x16x32_f16(a[m], b[n], acc[m][n], 0, 0, 0);
        }
        __syncthreads();    // drains stage loads (vmcnt 0) + all waves done reading cur
        cur ^= 1;
    }

    // Epilogue: C/D layout col=lane&15, row=(lane>>4)*4+reg  [m89/m91]; store f16.
#pragma unroll
    for (int m = 0; m < 4; ++m)
#pragma unroll
        for (int n = 0; n < 2; ++n) {
            const int col = bn + wn * 32 + n * 16 + lr;
            const int r0  = bm + wm * 64 + m * 16 + lg * 4;
#pragma unroll
            for (int j = 0; j < 4; ++j)
                C[(size_t)(r0 + j) * N + col] = f2h(acc[m][n][j]);
        }
}

// ---------------- fallback f32 GEMM (if ws too small) ----------------
#define GM_BM 128
#define GM_BN 64
#define GM_BK 16
#define GM_TM 8
#define GM_TN 4

__global__ __launch_bounds__(256) void gemm_qproj(const float* __restrict__ A,
                                                  const float* __restrict__ B,
                                                  float* __restrict__ C,
                                                  int M, int N, int K) {
    __shared__ float As[GM_BK][GM_BM];
    __shared__ float Bs[GM_BK][GM_BN];
    const int tid = threadIdx.x;
    const int tx = tid & 15;
    const int ty = tid >> 4;
    const int bm = blockIdx.x * GM_BM;
    const int bn = blockIdx.y * GM_BN;
    float acc[GM_TM][GM_TN];
#pragma unroll
    for (int i = 0; i < GM_TM; ++i)
#pragma unroll
        for (int j = 0; j < GM_TN; ++j) acc[i][j] = 0.f;
    for (int k0 = 0; k0 < K; k0 += GM_BK) {
#pragma unroll
        for (int i = 0; i < 2; ++i) {
            int idx = tid * 2 + i;
            int row = idx >> 2;
            int c4  = idx & 3;
            float4 v = *(const float4*)(A + (size_t)(bm + row) * K + k0 + c4 * 4);
            As[c4 * 4 + 0][row] = v.x;
            As[c4 * 4 + 1][row] = v.y;
            As[c4 * 4 + 2][row] = v.z;
            As[c4 * 4 + 3][row] = v.w;
        }
        {
            int row = tid >> 4;
            int c4  = tid & 15;
            float4 v = *(const float4*)(B + (size_t)(k0 + row) * N + bn + c4 * 4);
            *(float4*)&Bs[row][c4 * 4] = v;
        }
        __syncthreads();
#pragma unroll
        for (int k = 0; k < GM_BK; ++k) {
            float a[GM_TM], b[GM_TN];
#pragma unroll
            for (int i = 0; i < GM_TM; ++i) a[i] = As[k][ty * GM_TM + i];
#pragma unroll
            for (int j = 0; j < GM_TN; ++j) b[j] = Bs[k][tx * GM_TN + j];
#pragma unroll
            for (int i = 0; i < GM_TM; ++i)
#pragma unroll
                for (int j = 0; j < GM_TN; ++j) acc[i][j] += a[i] * b[j];
        }
        __syncthreads();
    }
#pragma unroll
    for (int i = 0; i < GM_TM; ++i) {
        float4 v;
        v.x = acc[i][0]; v.y = acc[i][1]; v.z = acc[i][2]; v.w = acc[i][3];
        *(float4*)(C + (size_t)(bm + ty * GM_TM + i) * N + bn + tx * GM_TN) = v;
    }
}

// ---------------- fused gather / score / softmax / output (f16 qproj) ----------------
__global__ __launch_bounds__(256) void attn_fused_h(const unsigned short* __restrict__ qf,
                                                    const int* __restrict__ sws,
                                                    const float* __restrict__ w2v,
                                                    float* __restrict__ out) {
    const int wave = threadIdx.x >> 6;
    const int lane = threadIdx.x & 63;
    const size_t row = (size_t)blockIdx.x * 4 + wave;

    // q row: 768 f16 = 192 8B-chunks, 3 per lane; chunk j covers the same
    // element range as the float4 chunks of the w2v rows.
    const ushort4* q4 = (const ushort4*)(qf + row * 768);
    float4 q[3];
#pragma unroll
    for (int j = 0; j < 3; ++j) {
        ushort4 h = q4[j * 64 + lane];
        q[j].x = h2f(h.x); q[j].y = h2f(h.y); q[j].z = h2f(h.z); q[j].w = h2f(h.w);
    }

    float4 ks[8][3];
    float dot[8];
#pragma unroll
    for (int k = 0; k < 8; ++k) {
        int id = sws[row * 8 + k];
        const float4* kp = (const float4*)(w2v + (size_t)id * 768);
        float d = 0.f;
#pragma unroll
        for (int j = 0; j < 3; ++j) {
            float4 v = kp[j * 64 + lane];
            ks[k][j] = v;
            d += q[j].x * v.x;
            d += q[j].y * v.y;
            d += q[j].z * v.z;
            d += q[j].w * v.w;
        }
        dot[k] = d;
    }
#pragma unroll
    for (int k = 0; k < 8; ++k) {
        float d = dot[k];
#pragma unroll
        for (int m = 1; m < 64; m <<= 1) d += __shfl_xor(d, m);
        dot[k] = d;
    }
    float mx = dot[0];
#pragma unroll
    for (int k = 1; k < 8; ++k) mx = fmaxf(mx, dot[k]);
    float w[8];
    float s = 0.f;
#pragma unroll
    for (int k = 0; k < 8; ++k) { w[k] = __expf(dot[k] - mx); s += w[k]; }
    const float inv = 1.f / s;

    float4 o[3];
#pragma unroll
    for (int j = 0; j < 3; ++j) { o[j].x = 0.f; o[j].y = 0.f; o[j].z = 0.f; o[j].w = 0.f; }
#pragma unroll
    for (int k = 0; k < 8; ++k) {
        const float a = w[k] * inv;
#pragma unroll
        for (int j = 0; j < 3; ++j) {
            o[j].x += a * ks[k][j].x;
            o[j].y += a * ks[k][j].y;
            o[j].z += a * ks[k][j].z;
            o[j].w += a * ks[k][j].w;
        }
    }
    float4* o4 = (float4*)(out + row * 768);
#pragma unroll
    for (int j = 0; j < 3; ++j) o4[j * 64 + lane] = o[j];
}

// f32-qproj variant for the fallback path.
__global__ __launch_bounds__(256) void attn_fused(const float* __restrict__ qproj,
                                                  const int* __restrict__ sws,
                                                  const float* __restrict__ w2v,
                                                  float* __restrict__ out) {
    const int wave = threadIdx.x >> 6;
    const int lane = threadIdx.x & 63;
    const size_t row = (size_t)blockIdx.x * 4 + wave;

    const float4* q4 = (const float4*)(qproj + row * 768);
    float4 q[3];
#pragma unroll
    for (int j = 0; j < 3; ++j) q[j] = q4[j * 64 + lane];

    float4 ks[8][3];
    float dot[8];
#pragma unroll
    for (int k = 0; k < 8; ++k) {
        int id = sws[row * 8 + k];
        const float4* kp = (const float4*)(w2v + (size_t)id * 768);
        float d = 0.f;
#pragma unroll
        for (int j = 0; j < 3; ++j) {
            float4 v = kp[j * 64 + lane];
            ks[k][j] = v;
            d += q[j].x * v.x + q[j].y * v.y + q[j].z * v.z + q[j].w * v.w;
        }
        dot[k] = d;
    }
#pragma unroll
    for (int k = 0; k < 8; ++k) {
        float d = dot[k];
#pragma unroll
        for (int m = 1; m < 64; m <<= 1) d += __shfl_xor(d, m);
        dot[k] = d;
    }
    float mx = dot[0];
#pragma unroll
    for (int k = 1; k < 8; ++k) mx = fmaxf(mx, dot[k]);
    float w[8];
    float s = 0.f;
#pragma unroll
    for (int k = 0; k < 8; ++k) { w[k] = __expf(dot[k] - mx); s += w[k]; }
    const float inv = 1.f / s;

    float4 o[3];
#pragma unroll
    for (int j = 0; j < 3; ++j) { o[j].x = 0.f; o[j].y = 0.f; o[j].z = 0.f; o[j].w = 0.f; }
#pragma unroll
    for (int k = 0; k < 8; ++k) {
        const float a = w[k] * inv;
#pragma unroll
        for (int j = 0; j < 3; ++j) {
            o[j].x += a * ks[k][j].x;
            o[j].y += a * ks[k][j].y;
            o[j].z += a * ks[k][j].z;
            o[j].w += a * ks[k][j].w;
        }
    }
    float4* o4 = (float4*)(out + row * 768);
#pragma unroll
    for (int j = 0; j < 3; ++j) o4[j * 64 + lane] = o[j];
}

extern "C" void kernel_launch(void* const* d_in, const int* in_sizes, int n_in,
                              void* d_out, int out_size, void* d_ws, size_t ws_size,
                              hipStream_t stream) {
    const float* hidden = (const float*)d_in[0];
    const int*   sws    = (const int*)d_in[1];
    const float* w2v    = (const float*)d_in[2];
    const float* weight = (const float*)d_in[3];
    float*       out    = (float*)d_out;

    const int E = 768;
    const int M = in_sizes[0] / E;            // 8192

    const size_t szA = (size_t)M * E;          // elements
    const size_t szB = (size_t)E * E;
    const size_t need = (2 * szA + szB) * sizeof(unsigned short);   // Af + Qf + WfT

    if (ws_size >= need) {
        unsigned short* Af  = (unsigned short*)d_ws;
        unsigned short* WfT = Af + szA;
        unsigned short* Qf  = WfT + szB;

        const int ablocks = 2048;
        const int wblocks = (E / 32) * (E / 32);   // 576
        split_all<<<ablocks + wblocks, 256, 0, stream>>>(
            (const float4*)hidden, (ushort4*)Af, M * E / 4,
            weight, WfT, E, E, ablocks);

        dim3 ggrid((M / BM) * (E / BN));      // 768 blocks, %8==0
        gemm_mfma_f16<<<ggrid, 256, 0, stream>>>(Af, WfT, Qf, M, E, E);

        attn_fused_h<<<dim3(M / 4), 256, 0, stream>>>(Qf, sws, w2v, out);
    } else {
        float* qproj = out;                   // staged through d_out
        dim3 ggrid(M / GM_BM, E / GM_BN);
        gemm_qproj<<<ggrid, 256, 0, stream>>>(hidden, weight, qproj, M, E, E);
        attn_fused<<<dim3(M / 4), 256, 0, stream>>>(qproj, sws, w2v, out);
    }
}